// Round 1
// baseline (3835.288 us; speedup 1.0000x reference)
//
#include <hip/hip_runtime.h>
#include <stdint.h>

// Conv4D: x(8,16,32,24,24,24) * W(32,16,3,3,3,3) -> out(8,32,30,22,22,22), + 3*b[o]
//
// x strides (elems):  n 7077888, c 442368, l 13824, d 576, h 24, w 1
// W strides:          o 1296, c 81, lk 27, dk 9, hk 3, wk 1
// out strides:        n 10222080, o 319440, l 10648, d 484, h 22, w 1

#define N_B   8
#define C_IN  16
#define C_OUT 32
#define L_OUT 30
#define D_OUT 22
#define H_OUT 22
#define W_OUT 22

#define X_N_STRIDE  7077888
#define X_C_STRIDE  442368
#define X_L_STRIDE  13824
#define X_D_STRIDE  576
#define O_N_STRIDE  10222080
#define O_O_STRIDE  319440
#define O_L_STRIDE  10648
#define O_D_STRIDE  484

#define W_ELEMS     (32 * 1296)
#define SLICE_ELEMS (C_IN * 576)   // one (c,h,w) slice: 16*24*24 = 9216 floats = 36 KB

typedef __attribute__((address_space(1))) const unsigned char ga_t;
typedef __attribute__((address_space(3))) unsigned char la_t;

// Pre-pass: W[o][r] (r = c*81+lk*27+dk*9+hk*3+wk) -> Wt[r][o] so the 32
// output-channel weights per tap are contiguous (s_load_dwordx16).
__global__ void transpose_w_kernel(const float* __restrict__ W, float* __restrict__ Wt) {
    int i = blockIdx.x * blockDim.x + threadIdx.x;
    if (i < W_ELEMS) {
        int o = i / 1296;
        int r = i - o * 1296;
        Wt[r * 32 + o] = W[i];
    }
}

// Async global->LDS staging of one 36 KB slice. LDS dest is linear in lane
// order (wave-uniform base + lane*16) as global_load_lds requires; global
// source addresses are per-lane (c-jumps handled per lane).
__device__ __forceinline__ void issue_slice_loads(const float* __restrict__ src,
                                                  float* dst,
                                                  const int* off_elems) {
    const int tid = threadIdx.x;
    #pragma unroll
    for (int k = 0; k < 5; ++k) {
        if (k < 4 || tid < 256) {   // e = tid*4 + k*2048 < 9216 ; wave-uniform branch
            const int e = tid * 4 + k * 2048;
            __builtin_amdgcn_global_load_lds((const ga_t*)(src + off_elems[k]),
                                             (la_t*)(dst + e), 16, 0, 0);
        }
    }
}

// One staged slice contributes to up to two output d-slices (acc0 = dd0,
// acc1 = dd0+1) with compile-time tap set {T0/DK0, T1/DK1}.
template <bool T0, int DK0, bool T1, int DK1, bool TRANSPOSED>
__device__ __forceinline__ void compute_stage(const float* __restrict__ sx,
                                              const float* __restrict__ wt,
                                              int lk, int ho, int wo,
                                              float* acc0, float* acc1) {
    const float* srow = sx + ho * 24 + wo;
    #pragma unroll 2
    for (int c = 0; c < C_IN; ++c) {
        #pragma unroll
        for (int hk = 0; hk < 3; ++hk) {
            #pragma unroll
            for (int wk = 0; wk < 3; ++wk) {
                const float xv = srow[c * 576 + hk * 24 + wk];
                const int rb = c * 81 + lk * 27 + hk * 3 + wk;   // + dk*9 per tap
                if (T0) {
                    if (TRANSPOSED) {
                        const float* wp = wt + ((rb + DK0 * 9) << 5);
                        #pragma unroll
                        for (int o = 0; o < C_OUT; ++o) acc0[o] = fmaf(xv, wp[o], acc0[o]);
                    } else {
                        const float* wp = wt + (rb + DK0 * 9);
                        #pragma unroll
                        for (int o = 0; o < C_OUT; ++o) acc0[o] = fmaf(xv, wp[o * 1296], acc0[o]);
                    }
                }
                if (T1) {
                    if (TRANSPOSED) {
                        const float* wp = wt + ((rb + DK1 * 9) << 5);
                        #pragma unroll
                        for (int o = 0; o < C_OUT; ++o) acc1[o] = fmaf(xv, wp[o], acc1[o]);
                    } else {
                        const float* wp = wt + (rb + DK1 * 9);
                        #pragma unroll
                        for (int o = 0; o < C_OUT; ++o) acc1[o] = fmaf(xv, wp[o * 1296], acc1[o]);
                    }
                }
            }
        }
    }
}

// Block = (n, lo, dd0..dd0+1), 512 threads (484 compute pixels).
// 12 staged slices (3 lk x 4 d) per 2 output d-slices, double-buffered LDS,
// global_load_lds prefetch of stage s+1 under compute of stage s, 1 barrier/stage.
template <bool TRANSPOSED>
__global__ __launch_bounds__(512, 4) void conv4d_kernel(
        const float* __restrict__ x,
        const float* __restrict__ wt,   // TRANSPOSED: [1296][32], else original [32][1296]
        const float* __restrict__ bias,
        float* __restrict__ out) {
    __shared__ float sx[2][SLICE_ELEMS];   // 2 x 36 KB

    const int DD2 = D_OUT / 2;             // 11
    const int bid = blockIdx.x;            // n*(30*11) + lo*11 + j
    const int n   = bid / (L_OUT * DD2);
    const int rem = bid - n * (L_OUT * DD2);
    const int lo  = rem / DD2;
    const int dd0 = (rem - lo * DD2) * 2;

    const int tid = threadIdx.x;
    const int ho  = tid / W_OUT;
    const int wo  = tid - ho * W_OUT;
    const bool active = tid < H_OUT * W_OUT;   // 484 compute threads

    // Per-thread staging offsets within a slice (constant across stages).
    int off_elems[5];
    #pragma unroll
    for (int k = 0; k < 5; ++k) {
        const int e = tid * 4 + k * 2048;
        if (e < SLICE_ELEMS) {
            const int c = e / 576;
            const int s = e - c * 576;
            off_elems[k] = c * X_C_STRIDE + s;
        } else {
            off_elems[k] = 0;
        }
    }

    float acc0[C_OUT], acc1[C_OUT];
    #pragma unroll
    for (int o = 0; o < C_OUT; ++o) {
        const float bv = 3.0f * bias[o];   // l_k bias contributions
        acc0[o] = bv;
        acc1[o] = bv;
    }

    const float* xb = x + (size_t)n * X_N_STRIDE + (size_t)lo * X_L_STRIDE
                    + (size_t)dd0 * X_D_STRIDE;

    // Prologue: stage (lk=0, off=0) into buffer 0.
    issue_slice_loads(xb, sx[0], off_elems);
    __syncthreads();   // drains vmcnt -> slice ready

    int cur = 0;
    #pragma unroll 1
    for (int lk = 0; lk < 3; ++lk) {
        const float* xbl = xb + (size_t)lk * X_L_STRIDE;

        // off = 0: d = dd0      -> taps: (acc0, dk=0)
        issue_slice_loads(xbl + 1 * X_D_STRIDE, sx[cur ^ 1], off_elems);
        if (active) compute_stage<true, 0, false, 0, TRANSPOSED>(sx[cur], wt, lk, ho, wo, acc0, acc1);
        __syncthreads();
        cur ^= 1;

        // off = 1: d = dd0+1    -> taps: (acc0, dk=1), (acc1, dk=0)
        issue_slice_loads(xbl + 2 * X_D_STRIDE, sx[cur ^ 1], off_elems);
        if (active) compute_stage<true, 1, true, 0, TRANSPOSED>(sx[cur], wt, lk, ho, wo, acc0, acc1);
        __syncthreads();
        cur ^= 1;

        // off = 2: d = dd0+2    -> taps: (acc0, dk=2), (acc1, dk=1)
        issue_slice_loads(xbl + 3 * X_D_STRIDE, sx[cur ^ 1], off_elems);
        if (active) compute_stage<true, 2, true, 1, TRANSPOSED>(sx[cur], wt, lk, ho, wo, acc0, acc1);
        __syncthreads();
        cur ^= 1;

        // off = 3: d = dd0+3    -> taps: (acc1, dk=2); prefetch next lk's off=0
        if (lk < 2) issue_slice_loads(xbl + X_L_STRIDE, sx[cur ^ 1], off_elems);
        if (active) compute_stage<false, 0, true, 2, TRANSPOSED>(sx[cur], wt, lk, ho, wo, acc0, acc1);
        __syncthreads();
        cur ^= 1;
    }

    if (active) {
        float* ob = out + (size_t)n * O_N_STRIDE + (size_t)lo * O_L_STRIDE
                  + (size_t)dd0 * O_D_STRIDE + ho * W_OUT + wo;
        #pragma unroll
        for (int o = 0; o < C_OUT; ++o) {
            ob[(size_t)o * O_O_STRIDE]               = acc0[o];
            ob[(size_t)o * O_O_STRIDE + O_D_STRIDE]  = acc1[o];
        }
    }
}

extern "C" void kernel_launch(void* const* d_in, const int* in_sizes, int n_in,
                              void* d_out, int out_size, void* d_ws, size_t ws_size,
                              hipStream_t stream) {
    const float* x = (const float*)d_in[0];
    const float* W = (const float*)d_in[1];
    const float* b = (const float*)d_in[2];
    float* out = (float*)d_out;

    const int grid = N_B * L_OUT * (D_OUT / 2);   // 2640 blocks

    if (ws_size >= W_ELEMS * sizeof(float)) {
        float* Wt = (float*)d_ws;
        transpose_w_kernel<<<(W_ELEMS + 255) / 256, 256, 0, stream>>>(W, Wt);
        conv4d_kernel<true><<<grid, 512, 0, stream>>>(x, Wt, b, out);
    } else {
        conv4d_kernel<false><<<grid, 512, 0, stream>>>(x, W, b, out);
    }
}

// Round 2
// 2477.133 us; speedup vs baseline: 1.5483x; 1.5483x over previous
//
#include <hip/hip_runtime.h>
#include <stdint.h>

// Conv4D: x(8,16,32,24,24,24) * W(32,16,3,3,3,3) -> out(8,32,30,22,22,22), + 3*b[o]
//
// x strides (elems):  n 7077888, c 442368, l 13824, d 576, h 24, w 1
// W strides:          o 1296, c 81, lk 27, dk 9, hk 3, wk 1
// out strides:        n 10222080, o 319440, l 10648, d 484, h 22, w 1

#define N_B   8
#define C_IN  16
#define C_OUT 32
#define L_OUT 30
#define D_OUT 22
#define H_OUT 22
#define W_OUT 22

#define X_N_STRIDE  7077888
#define X_C_STRIDE  442368
#define X_L_STRIDE  13824
#define X_D_STRIDE  576
#define O_N_STRIDE  10222080
#define O_O_STRIDE  319440
#define O_L_STRIDE  10648
#define O_D_STRIDE  484

#define W_ELEMS   (32 * 1296)
#define C_HALF    8
#define HS_ELEMS  (C_HALF * 576)   // half-channel slice: 8*24*24 = 4608 floats = 18 KB

typedef __attribute__((address_space(1))) const unsigned char ga_t;
typedef __attribute__((address_space(3))) unsigned char la_t;

// Pre-pass: W[o][r] (r = c*81+lk*27+dk*9+hk*3+wk) -> Wt[r][o] so the 32
// output-channel weights per tap are contiguous (scalar s_load_dwordx16 path).
__global__ void transpose_w_kernel(const float* __restrict__ W, float* __restrict__ Wt) {
    int i = blockIdx.x * blockDim.x + threadIdx.x;
    if (i < W_ELEMS) {
        int o = i / 1296;
        int r = i - o * 1296;
        Wt[r * 32 + o] = W[i];
    }
}

// Async global->LDS staging of one 18 KB half-slice (8 channels x 24 x 24).
// LDS dest is linear in lane order (wave-uniform base + lane*16) as
// global_load_lds requires; per-lane global source handles the c-jumps.
// 4608 floats = 1152 dwordx4: k=0,1 all 512 threads, k=2 threads 0..127.
__device__ __forceinline__ void issue_half(const float* __restrict__ src,
                                           float* dst, const int* off_elems) {
    const int tid = threadIdx.x;
    #pragma unroll
    for (int k = 0; k < 3; ++k) {
        if (k < 2 || tid < 128) {   // wave-uniform branch (k=2 -> waves 0,1)
            const int e = tid * 4 + k * 2048;
            __builtin_amdgcn_global_load_lds((const ga_t*)(src + off_elems[k]),
                                             (la_t*)(dst + e), 16, 0, 0);
        }
    }
}

// Accumulate one staged half-slice into acc[32].
// rbase = ch*8*81 + lk*27 + dk*9 (uniform); tap r = rbase + cl*81 + hk*3 + wk.
template <bool TRANSPOSED>
__device__ __forceinline__ void compute_half(const float* __restrict__ sxb,
                                             const float* __restrict__ wt,
                                             int rbase, int ho, int wo,
                                             float* acc) {
    const float* srow = sxb + ho * 24 + wo;
    #pragma unroll 2
    for (int cl = 0; cl < C_HALF; ++cl) {
        #pragma unroll
        for (int hk = 0; hk < 3; ++hk) {
            #pragma unroll
            for (int wk = 0; wk < 3; ++wk) {
                const float xv = srow[cl * 576 + hk * 24 + wk];
                const int r = rbase + cl * 81 + hk * 3 + wk;
                if (TRANSPOSED) {
                    const float* wp = wt + (r << 5);
                    #pragma unroll
                    for (int o = 0; o < C_OUT; ++o)
                        acc[o] = fmaf(xv, wp[o], acc[o]);
                } else {
                    const float* wp = wt + r;
                    #pragma unroll
                    for (int o = 0; o < C_OUT; ++o)
                        acc[o] = fmaf(xv, wp[o * 1296], acc[o]);
                }
            }
        }
    }
}

// Block = (n, lo, dd), 512 threads (484 compute pixels).
// 18 staging phases split into 36 half-slices, double-buffered in 36 KB LDS
// (same footprint as the 2851us baseline -> 4 blocks/CU), with the next
// half-slice's global_load_lds issued before the current compute so the
// vmcnt(0) drain at each barrier is covered by ~9k cycles of FMA.
template <bool TRANSPOSED>
__global__ __launch_bounds__(512, 8) void conv4d_kernel(
        const float* __restrict__ x,
        const float* __restrict__ wt,   // TRANSPOSED: [1296][32], else original [32][1296]
        const float* __restrict__ bias,
        float* __restrict__ out) {
    __shared__ float sx[2][HS_ELEMS];   // 2 x 18 KB

    const int bid = blockIdx.x;                // n * (30*22) + lo * 22 + dd
    const int n   = bid / (L_OUT * D_OUT);
    const int rem = bid - n * (L_OUT * D_OUT);
    const int lo  = rem / D_OUT;
    const int dd  = rem - lo * D_OUT;

    const int tid = threadIdx.x;
    const int ho  = tid / W_OUT;
    const int wo  = tid - ho * W_OUT;
    const bool active = tid < H_OUT * W_OUT;   // 484 compute threads

    // Per-thread staging offsets within a half-slice (constant across stages).
    int off_elems[3];
    #pragma unroll
    for (int k = 0; k < 3; ++k) {
        const int e = tid * 4 + k * 2048;
        if (e < HS_ELEMS) {
            const int c = e / 576;
            const int s = e - c * 576;
            off_elems[k] = c * X_C_STRIDE + s;
        } else {
            off_elems[k] = 0;
        }
    }

    float acc[C_OUT];
    #pragma unroll
    for (int o = 0; o < C_OUT; ++o) acc[o] = 3.0f * bias[o];  // l_k bias contributions

    const float* xb = x + (size_t)n * X_N_STRIDE + (size_t)lo * X_L_STRIDE
                    + (size_t)dd * X_D_STRIDE;

    // Prologue: stage (lk=0, dk=0, ch=0) into buffer 0.
    issue_half(xb, sx[0], off_elems);
    __syncthreads();   // drains vmcnt -> half-slice ready

    int cur = 0;
    #pragma unroll 1
    for (int lk = 0; lk < 3; ++lk) {
        #pragma unroll 1
        for (int dk = 0; dk < 3; ++dk) {
            #pragma unroll 1
            for (int ch = 0; ch < 2; ++ch) {
                // Next stage coords (ch fastest, then dk, then lk).
                int nch = ch ^ 1, ndk = dk, nlk = lk;
                if (nch == 0) { ndk = dk + 1; if (ndk == 3) { ndk = 0; nlk = lk + 1; } }

                if (nlk < 3) {
                    const float* nsrc = xb + (size_t)nlk * X_L_STRIDE
                                      + (size_t)ndk * X_D_STRIDE
                                      + (size_t)nch * (C_HALF * X_C_STRIDE);
                    issue_half(nsrc, sx[cur ^ 1], off_elems);
                }

                if (active) {
                    const int rbase = ch * (C_HALF * 81) + lk * 27 + dk * 9;
                    compute_half<TRANSPOSED>(sx[cur], wt, rbase, ho, wo, acc);
                }

                __syncthreads();   // compiler emits vmcnt(0) drain: next slice ready
                cur ^= 1;
            }
        }
    }

    if (active) {
        float* ob = out + (size_t)n * O_N_STRIDE + (size_t)lo * O_L_STRIDE
                  + (size_t)dd * O_D_STRIDE + ho * W_OUT + wo;
        #pragma unroll
        for (int o = 0; o < C_OUT; ++o) ob[(size_t)o * O_O_STRIDE] = acc[o];
    }
}

extern "C" void kernel_launch(void* const* d_in, const int* in_sizes, int n_in,
                              void* d_out, int out_size, void* d_ws, size_t ws_size,
                              hipStream_t stream) {
    const float* x = (const float*)d_in[0];
    const float* W = (const float*)d_in[1];
    const float* b = (const float*)d_in[2];
    float* out = (float*)d_out;

    const int grid = N_B * L_OUT * D_OUT;  // 5280 blocks

    if (ws_size >= W_ELEMS * sizeof(float)) {
        float* Wt = (float*)d_ws;
        transpose_w_kernel<<<(W_ELEMS + 255) / 256, 256, 0, stream>>>(W, Wt);
        conv4d_kernel<true><<<grid, 512, 0, stream>>>(x, Wt, b, out);
    } else {
        conv4d_kernel<false><<<grid, 512, 0, stream>>>(x, W, b, out);
    }
}

// Round 3
// 1011.468 us; speedup vs baseline: 3.7918x; 2.4490x over previous
//
#include <hip/hip_runtime.h>
#include <stdint.h>

// Conv4D: x(8,16,32,24,24,24) * W(32,16,3,3,3,3) -> out(8,32,30,22,22,22), + 3*b[o]
// MFMA path: 3-product bf16 split (xh*wh + xh*wl + xl*wh), implicit GEMM
//   M=32 (C_OUT), N=pixels, K=1296, mfma_f32_16x16x32_bf16.
// Pre-pass 1: W -> per-lane A-fragment table wf[9][5][2][2][64][8] bf16 (global ws)
// Pre-pass 2: x -> xt[n][l][d] slices [sp2][cc2][h24][w24][c8] bf16 (global ws)
// Main: per block (n,lo,dd): 9 staged slices (global_load_lds, double-buffered),
//   5 tap-pairs x (2 B-reads + 6 MFMA) x 4 N-tiles per wave.
// Fallback (ws too small): round-2 vector kernel (2410us) verbatim.

#define N_B   8
#define C_IN  16
#define C_OUT 32
#define L_IN  32
#define D_IN  24
#define L_OUT 30
#define D_OUT 22
#define H_OUT 22
#define W_OUT 22

#define X_N_STRIDE  7077888
#define X_C_STRIDE  442368
#define X_L_STRIDE  13824
#define X_D_STRIDE  576
#define O_N_STRIDE  10222080
#define O_O_STRIDE  319440
#define O_L_STRIDE  10648
#define O_D_STRIDE  484

#define W_ELEMS   (32 * 1296)

// xt slice: [sp(2)][cc(2)][h(24)][w(24)][c8(8)] bf16 = 18432 shorts = 36864 B
#define SLICE_SHORTS 18432
#define SLICE_BYTES  36864
#define XT_SLICES    (N_B * L_IN * D_IN)                    // 6144
#define XT_BYTES     ((size_t)XT_SLICES * SLICE_BYTES)      // 226,492,416

// wf: [s(9)][pp(5)][sp(2)][mt(2)][lane(64)][i(8)] bf16
#define WF_SHORTS (9 * 5 * 2 * 2 * 64 * 8)                  // 92160
#define WF_BYTES  ((size_t)WF_SHORTS * 2)                   // 184320

typedef __attribute__((ext_vector_type(8))) short short8;
typedef __attribute__((ext_vector_type(4))) float f32x4;
typedef __attribute__((address_space(1))) const unsigned char ga_t;
typedef __attribute__((address_space(3))) unsigned char la_t;

static __device__ __forceinline__ unsigned short f32_bf16_rne(float f) {
    uint32_t u = __float_as_uint(f);
    uint32_t r = u + 0x7fffu + ((u >> 16) & 1u);
    return (unsigned short)(r >> 16);
}
static __device__ __forceinline__ float bf16_f32(unsigned short h) {
    return __uint_as_float(((uint32_t)h) << 16);
}

// ---------------- pre-pass 1: weight fragments -------------------------------
// idx = ((((s*5+pp)*2+sp)*2+mt)*64 + l)*8 + i
// A-frag element: lane l, elem i -> A[m = mt*16 + (l&15)][k = (l>>4)*8 + i]
// k in [0,32): tap_local = k>>4 (pair member), c = k&15. tap t = pp*2+tap_local.
// t==9 (pad of pair 4) -> 0 so garbage B contributes nothing.
__global__ void prep_w_kernel(const float* __restrict__ W, unsigned short* __restrict__ wf) {
    int idx = blockIdx.x * blockDim.x + threadIdx.x;
    if (idx >= WF_SHORTS) return;
    const int i  = idx & 7;
    const int l  = (idx >> 3) & 63;
    const int mt = (idx >> 9) & 1;
    const int sp = (idx >> 10) & 1;
    const int pp = (idx >> 11) % 5;
    const int s  = (idx >> 11) / 5;
    const int q  = l >> 4;
    const int m  = mt * 16 + (l & 15);
    const int k  = q * 8 + i;
    const int t  = pp * 2 + (k >> 4);
    const int c  = k & 15;
    unsigned short v = 0;
    if (t < 9) {
        const int lk = s / 3, dk = s % 3, hk = t / 3, wk = t % 3;
        const float w = W[m * 1296 + c * 81 + lk * 27 + dk * 9 + hk * 3 + wk];
        const unsigned short hi = f32_bf16_rne(w);
        v = (sp == 0) ? hi : f32_bf16_rne(w - bf16_f32(hi));
    }
    wf[idx] = v;
}

// ---------------- pre-pass 2: x transpose + bf16 split -----------------------
// block = (n*L_IN + l)*D_IN + d ; thread = h*24 + w (576 threads)
__global__ void prep_x_kernel(const float* __restrict__ x, unsigned short* __restrict__ xt) {
    const int b  = blockIdx.x;
    const int d  = b % D_IN;
    const int t2 = b / D_IN;
    const int lx = t2 % L_IN;
    const int n  = t2 / L_IN;
    const int hw = threadIdx.x;   // 0..575
    const float* xp = x + (size_t)n * X_N_STRIDE + (size_t)lx * X_L_STRIDE
                    + (size_t)d * X_D_STRIDE + hw;
    unsigned short hi[16], lo[16];
    #pragma unroll
    for (int c = 0; c < 16; ++c) {
        const float v = xp[(size_t)c * X_C_STRIDE];
        hi[c] = f32_bf16_rne(v);
        lo[c] = f32_bf16_rne(v - bf16_f32(hi[c]));
    }
    unsigned short* sl = xt + (size_t)b * SLICE_SHORTS + hw * 8;
    #pragma unroll
    for (int sp = 0; sp < 2; ++sp) {
        #pragma unroll
        for (int cc = 0; cc < 2; ++cc) {
            short8 v;
            #pragma unroll
            for (int i = 0; i < 8; ++i)
                v[i] = (short)(sp ? lo[cc * 8 + i] : hi[cc * 8 + i]);
            *(short8*)(sl + (sp * 2 + cc) * 4608) = v;  // region stride 4608 shorts
        }
    }
}

// ---------------- main MFMA kernel -------------------------------------------
// Stage slice (byte-exact copy, linear lane order): tid*16 + k*8192, k=0..3 all,
// k=4 only tid<256 (36864 B total).
#define STAGE(SPTR, BUFP) do {                                                   \
    const char* _src = (const char*)(SPTR);                                      \
    char* _dst = (char*)(BUFP);                                                  \
    const int _off = tid * 16;                                                   \
    _Pragma("unroll")                                                            \
    for (int _k = 0; _k < 4; ++_k)                                               \
        __builtin_amdgcn_global_load_lds((const ga_t*)(_src + _off + _k * 8192), \
                                         (la_t*)(_dst + _off + _k * 8192), 16, 0, 0); \
    if (tid < 256)                                                               \
        __builtin_amdgcn_global_load_lds((const ga_t*)(_src + _off + 32768),     \
                                         (la_t*)(_dst + _off + 32768), 16, 0, 0); \
} while (0)

__global__ __launch_bounds__(512, 4) void conv4d_mfma(
        const unsigned short* __restrict__ xt,
        const unsigned short* __restrict__ wf,
        const float* __restrict__ bias,
        float* __restrict__ out) {
    __shared__ __align__(16) unsigned short ss[2][SLICE_SHORTS];  // 2 x 36 KB

    const int bid = blockIdx.x;                // n*(30*22) + lo*22 + dd
    const int n   = bid / (L_OUT * D_OUT);
    const int rem = bid - n * (L_OUT * D_OUT);
    const int lo  = rem / D_OUT;
    const int dd  = rem - lo * D_OUT;

    const int tid = threadIdx.x;
    const int wv  = tid >> 6;                  // wave 0..7
    const int l   = tid & 63;
    const int j   = l & 15;                    // B/D column (pixel within tile)
    const int q   = l >> 4;                    // lane quarter

    // Per-lane pixel byte-addresses (within a [h][w][c8] region), 4 N-tiles/wave.
    int pixaddr[4];
    #pragma unroll
    for (int tt = 0; tt < 4; ++tt) {
        int p = (wv * 4 + tt) * 16 + j;
        const int pc = p < 484 ? p : 483;      // clamp pad pixels (store-masked)
        const int ho = pc / 22, wo = pc - ho * 22;
        pixaddr[tt] = (ho * 24 + wo) * 16;
    }
    // Per-lane tap offsets per pair: quarter q reads tap pp*2 + (q>>1), chunk q&1.
    int toff[5];
    #pragma unroll
    for (int pp = 0; pp < 5; ++pp) {
        int t = pp * 2 + (q >> 1); if (t > 8) t = 8;   // pad pair reads tap 8 (A=0)
        const int hk = t / 3, wk = t - hk * 3;
        toff[pp] = (q & 1) * 9216 + (hk * 24 + wk) * 16;
    }

    f32x4 acc[2][4];
    #pragma unroll
    for (int mt = 0; mt < 2; ++mt)
        #pragma unroll
        for (int tt = 0; tt < 4; ++tt)
            acc[mt][tt] = (f32x4){0.f, 0.f, 0.f, 0.f};

    const unsigned short* xbase = xt + (size_t)((n * L_IN + lo) * D_IN + dd) * SLICE_SHORTS;
    const short8* wfv = (const short8*)wf;

    STAGE(xbase, &ss[0][0]);                   // s=0: (lk,dk)=(0,0)
    __syncthreads();                           // vmcnt(0) drain -> slice ready

    #pragma unroll 1
    for (int s = 0; s < 9; ++s) {
        const int buf = s & 1;
        if (s < 8) {                           // prefetch next slice into other buf
            const int s1 = s + 1;
            const int lk1 = s1 / 3, dk1 = s1 - lk1 * 3;
            STAGE(xbase + (size_t)(lk1 * D_IN + dk1) * SLICE_SHORTS, &ss[buf ^ 1][0]);
        }
        const char* sb = (const char*)(&ss[buf][0]);
        #pragma unroll
        for (int pp = 0; pp < 5; ++pp) {
            const int fb = (s * 5 + pp) * 256 + l;
            const short8 ah0 = wfv[fb];        // sp=hi, mt=0
            const short8 ah1 = wfv[fb + 64];   // sp=hi, mt=1
            const short8 al0 = wfv[fb + 128];  // sp=lo, mt=0
            const short8 al1 = wfv[fb + 192];  // sp=lo, mt=1
            #pragma unroll
            for (int tt = 0; tt < 4; ++tt) {
                const char* bp = sb + (pixaddr[tt] + toff[pp]);
                const short8 bh = *(const short8*)(bp);            // x_hi
                const short8 bl = *(const short8*)(bp + 18432);    // x_lo
                acc[0][tt] = __builtin_amdgcn_mfma_f32_16x16x32_bf16(ah0, bh, acc[0][tt], 0, 0, 0);
                acc[1][tt] = __builtin_amdgcn_mfma_f32_16x16x32_bf16(ah1, bh, acc[1][tt], 0, 0, 0);
                acc[0][tt] = __builtin_amdgcn_mfma_f32_16x16x32_bf16(al0, bh, acc[0][tt], 0, 0, 0);
                acc[1][tt] = __builtin_amdgcn_mfma_f32_16x16x32_bf16(al1, bh, acc[1][tt], 0, 0, 0);
                acc[0][tt] = __builtin_amdgcn_mfma_f32_16x16x32_bf16(ah0, bl, acc[0][tt], 0, 0, 0);
                acc[1][tt] = __builtin_amdgcn_mfma_f32_16x16x32_bf16(ah1, bl, acc[1][tt], 0, 0, 0);
            }
        }
        __syncthreads();
    }

    // Epilogue: D col = lane&15 (pixel), row = q*4 + reg (verified C/D layout).
    const int o0 = q * 4;
    float bv[2][4];
    #pragma unroll
    for (int mt = 0; mt < 2; ++mt)
        #pragma unroll
        for (int r = 0; r < 4; ++r)
            bv[mt][r] = 3.0f * bias[mt * 16 + o0 + r];
    float* ob = out + (size_t)n * O_N_STRIDE + (size_t)lo * O_L_STRIDE + (size_t)dd * O_D_STRIDE;
    #pragma unroll
    for (int tt = 0; tt < 4; ++tt) {
        const int p = (wv * 4 + tt) * 16 + j;
        if (p < 484) {
            #pragma unroll
            for (int mt = 0; mt < 2; ++mt)
                #pragma unroll
                for (int r = 0; r < 4; ++r)
                    ob[(size_t)(mt * 16 + o0 + r) * O_O_STRIDE + p] = acc[mt][tt][r] + bv[mt][r];
        }
    }
}

// ---------------- fallback: round-2 vector kernel (2410us, proven) -----------
__global__ void transpose_w_kernel(const float* __restrict__ W, float* __restrict__ Wt) {
    int i = blockIdx.x * blockDim.x + threadIdx.x;
    if (i < W_ELEMS) {
        int o = i / 1296;
        int r = i - o * 1296;
        Wt[r * 32 + o] = W[i];
    }
}

#define C_HALF    8
#define HS_ELEMS  (C_HALF * 576)

__device__ __forceinline__ void issue_half(const float* __restrict__ src,
                                           float* dst, const int* off_elems) {
    const int tid = threadIdx.x;
    #pragma unroll
    for (int k = 0; k < 3; ++k) {
        if (k < 2 || tid < 128) {
            const int e = tid * 4 + k * 2048;
            __builtin_amdgcn_global_load_lds((const ga_t*)(src + off_elems[k]),
                                             (la_t*)(dst + e), 16, 0, 0);
        }
    }
}

template <bool TRANSPOSED>
__device__ __forceinline__ void compute_half(const float* __restrict__ sxb,
                                             const float* __restrict__ wt,
                                             int rbase, int ho, int wo,
                                             float* acc) {
    const float* srow = sxb + ho * 24 + wo;
    #pragma unroll 2
    for (int cl = 0; cl < C_HALF; ++cl) {
        #pragma unroll
        for (int hk = 0; hk < 3; ++hk) {
            #pragma unroll
            for (int wk = 0; wk < 3; ++wk) {
                const float xv = srow[cl * 576 + hk * 24 + wk];
                const int r = rbase + cl * 81 + hk * 3 + wk;
                if (TRANSPOSED) {
                    const float* wp = wt + (r << 5);
                    #pragma unroll
                    for (int o = 0; o < C_OUT; ++o) acc[o] = fmaf(xv, wp[o], acc[o]);
                } else {
                    const float* wp = wt + r;
                    #pragma unroll
                    for (int o = 0; o < C_OUT; ++o) acc[o] = fmaf(xv, wp[o * 1296], acc[o]);
                }
            }
        }
    }
}

template <bool TRANSPOSED>
__global__ __launch_bounds__(512, 8) void conv4d_vec(
        const float* __restrict__ x,
        const float* __restrict__ wt,
        const float* __restrict__ bias,
        float* __restrict__ out) {
    __shared__ float sx[2][HS_ELEMS];

    const int bid = blockIdx.x;
    const int n   = bid / (L_OUT * D_OUT);
    const int rem = bid - n * (L_OUT * D_OUT);
    const int lo  = rem / D_OUT;
    const int dd  = rem - lo * D_OUT;

    const int tid = threadIdx.x;
    const int ho  = tid / W_OUT;
    const int wo  = tid - ho * W_OUT;
    const bool active = tid < H_OUT * W_OUT;

    int off_elems[3];
    #pragma unroll
    for (int k = 0; k < 3; ++k) {
        const int e = tid * 4 + k * 2048;
        if (e < HS_ELEMS) {
            const int c = e / 576;
            const int sref = e - c * 576;
            off_elems[k] = c * X_C_STRIDE + sref;
        } else off_elems[k] = 0;
    }

    float acc[C_OUT];
    #pragma unroll
    for (int o = 0; o < C_OUT; ++o) acc[o] = 3.0f * bias[o];

    const float* xb = x + (size_t)n * X_N_STRIDE + (size_t)lo * X_L_STRIDE
                    + (size_t)dd * X_D_STRIDE;

    issue_half(xb, sx[0], off_elems);
    __syncthreads();

    int cur = 0;
    #pragma unroll 1
    for (int lk = 0; lk < 3; ++lk) {
        #pragma unroll 1
        for (int dk = 0; dk < 3; ++dk) {
            #pragma unroll 1
            for (int ch = 0; ch < 2; ++ch) {
                int nch = ch ^ 1, ndk = dk, nlk = lk;
                if (nch == 0) { ndk = dk + 1; if (ndk == 3) { ndk = 0; nlk = lk + 1; } }
                if (nlk < 3) {
                    const float* nsrc = xb + (size_t)nlk * X_L_STRIDE
                                      + (size_t)ndk * X_D_STRIDE
                                      + (size_t)nch * (C_HALF * X_C_STRIDE);
                    issue_half(nsrc, sx[cur ^ 1], off_elems);
                }
                if (active) {
                    const int rbase = ch * (C_HALF * 81) + lk * 27 + dk * 9;
                    compute_half<TRANSPOSED>(sx[cur], wt, rbase, ho, wo, acc);
                }
                __syncthreads();
                cur ^= 1;
            }
        }
    }

    if (active) {
        float* ob = out + (size_t)n * O_N_STRIDE + (size_t)lo * O_L_STRIDE
                  + (size_t)dd * O_D_STRIDE + ho * W_OUT + wo;
        #pragma unroll
        for (int o = 0; o < C_OUT; ++o) ob[(size_t)o * O_O_STRIDE] = acc[o];
    }
}

// ---------------- launcher ---------------------------------------------------
extern "C" void kernel_launch(void* const* d_in, const int* in_sizes, int n_in,
                              void* d_out, int out_size, void* d_ws, size_t ws_size,
                              hipStream_t stream) {
    const float* x = (const float*)d_in[0];
    const float* W = (const float*)d_in[1];
    const float* b = (const float*)d_in[2];
    float* out = (float*)d_out;

    const int grid = N_B * L_OUT * D_OUT;  // 5280 blocks

    if (ws_size >= WF_BYTES + XT_BYTES) {
        unsigned short* wf = (unsigned short*)d_ws;
        unsigned short* xtb = (unsigned short*)((char*)d_ws + WF_BYTES);  // 184320 % 256 == 0
        prep_w_kernel<<<(WF_SHORTS + 255) / 256, 256, 0, stream>>>(W, wf);
        prep_x_kernel<<<XT_SLICES, 576, 0, stream>>>(x, xtb);
        conv4d_mfma<<<grid, 512, 0, stream>>>(xtb, wf, b, out);
    } else if (ws_size >= W_ELEMS * sizeof(float)) {
        float* Wt = (float*)d_ws;
        transpose_w_kernel<<<(W_ELEMS + 255) / 256, 256, 0, stream>>>(W, Wt);
        conv4d_vec<true><<<grid, 512, 0, stream>>>(x, Wt, b, out);
    } else {
        conv4d_vec<false><<<grid, 512, 0, stream>>>(x, W, b, out);
    }
}